// Round 13
// baseline (198.069 us; speedup 1.0000x reference)
//
#include <hip/hip_runtime.h>

typedef __attribute__((ext_vector_type(8))) short short8;
typedef __attribute__((ext_vector_type(4))) float f32x4;
typedef unsigned int u32;

#define D_ 256
#define QT_V 3000
#define QR_V 216
#define QO_V 1
#define QPT 3008          // padded head-t rows (94 tiles)
#define QPR 224           // padded head-r rows (7 tiles)
#define QPO 96            // padded head-o rows (3 tiles)
#define QPTOT 3328        // 26 * 128
#define NQB 26            // attn qblocks of 128 cols
#define WQ_TILES 104
#define NSPLIT 8          /* measured best: 8 > {5,16} */
#define VPAD 32
#define SCALE 0.09016844005556021f   /* log2(e)/16 */
#define TILE_US 8192      /* ushorts per 32x256 bf16 frag-linear tile */
#define PSTRIDE 264       /* padded LDS row stride in ushorts */

__device__ __forceinline__ unsigned short f2bf(float f) {
    union { float f; unsigned int i; } u; u.f = f;
    unsigned int i = u.i + 0x7fffu + ((u.i >> 16) & 1u);
    return (unsigned short)(i >> 16);
}

__device__ __forceinline__ void async_cp16(const unsigned short* g, unsigned short* l) {
    __builtin_amdgcn_global_load_lds((const __attribute__((address_space(1))) u32*)g,
                                     (__attribute__((address_space(3))) u32*)l, 16, 0, 0);
}

// ---------------- prep: ONE launch, fully independent block families --------
// [0, nvs): vsum blocks — each computes its own wvsum (L2-hot Wv) then 128
//           feat rows; block 0 also zeroes vsum pads. Scheduled FIRST so the
//           serial row passes overlap the rest of the grid (R7 had them last).
// [nvs, +ntiles): feat f32 -> bf16 frag-linear featb (no vsum work)
// [nvs+ntiles, +WQ_TILES): WqT GEMM (self-converts Wk f32->bf16)
__global__ __launch_bounds__(256) void prep(
    const float* __restrict__ feat,
    const float* __restrict__ q_t, const float* __restrict__ q_r,
    const float* __restrict__ q_o,
    const float* __restrict__ wk_t, const float* __restrict__ wk_r,
    const float* __restrict__ wk_o,
    const float* __restrict__ wv_t, const float* __restrict__ wv_r,
    const float* __restrict__ wv_o,
    unsigned short* __restrict__ featb,
    float* __restrict__ vsum,
    unsigned short* __restrict__ WqT,
    int N, int ntiles, int nvs)
{
    __shared__ __align__(16) unsigned short lds[32 * PSTRIDE];
    int blk = blockIdx.x, tid = (int)threadIdx.x;
    int srow = tid >> 3, c8 = tid & 7;
    int wave = tid >> 6, lane = tid & 63;
    int col16 = lane & 15, quad = lane >> 4;

    if (blk < nvs) {
        // ---- vsum block: private wvsum then 128 rows ----
        int v = blk;
        float* wv = (float*)lds;   // 768 floats
        for (int f0 = wave * 4; f0 < 768; f0 += 16) {
            int f = f0 + (lane >> 4);
            int hh = f >> 8, c = f & 255;
            const float* base = ((hh == 0) ? wv_t : (hh == 1) ? wv_r : wv_o)
                                + (size_t)c * D_;
            float s = 0.f;
#pragma unroll
            for (int p = 0; p < 4; ++p) {
                float4 x = *(const float4*)(base + p * 64 + (lane & 15) * 4);
                s += x.x + x.y + x.z + x.w;
            }
            s += __shfl_xor(s, 1); s += __shfl_xor(s, 2);
            s += __shfl_xor(s, 4); s += __shfl_xor(s, 8);
            if ((lane & 15) == 0) wv[f] = s;
        }
        __syncthreads();
        if (v == 0 && tid < 3 * VPAD) {
            int hh = tid / VPAD, i = tid % VPAD;
            vsum[(size_t)hh * (N + VPAD) + N + i] = 0.f;
        }
        int r0 = v * 128;
#pragma unroll 1
        for (int pass = 0; pass < 32; ++pass) {
            int row = r0 + pass * 4 + wave;
            if (row < N) {
                float4 fv = *(const float4*)(feat + (size_t)row * D_ + lane * 4);
                float4 w0 = *(const float4*)(wv + lane * 4);
                float4 w1 = *(const float4*)(wv + 256 + lane * 4);
                float4 w2 = *(const float4*)(wv + 512 + lane * 4);
                float p0 = fv.x * w0.x + fv.y * w0.y + fv.z * w0.z + fv.w * w0.w;
                float p1 = fv.x * w1.x + fv.y * w1.y + fv.z * w1.z + fv.w * w1.w;
                float p2 = fv.x * w2.x + fv.y * w2.y + fv.z * w2.z + fv.w * w2.w;
#pragma unroll
                for (int off = 32; off >= 1; off >>= 1) {
                    p0 += __shfl_xor(p0, off);
                    p1 += __shfl_xor(p1, off);
                    p2 += __shfl_xor(p2, off);
                }
                if (lane == 0) {
                    vsum[0 * (size_t)(N + VPAD) + row] = p0;
                    vsum[1 * (size_t)(N + VPAD) + row] = p1;
                    vsum[2 * (size_t)(N + VPAD) + row] = p2;
                }
            }
        }
    } else if (blk < nvs + ntiles) {
        // ---- feat tile: coalesced f32 load -> bf16 LDS -> frag swizzle ----
        int t = blk - nvs;
        int row = t * 32 + srow;
        bool valid = row < N;
#pragma unroll
        for (int i = 0; i < 8; ++i) {
            int col = i * 32 + c8 * 4;
            float4 v;
            if (valid) v = *(const float4*)(feat + (size_t)row * D_ + col);
            else { v.x = v.y = v.z = v.w = 0.f; }
            ushort4 o;
            o.x = f2bf(v.x); o.y = f2bf(v.y); o.z = f2bf(v.z); o.w = f2bf(v.w);
            *(ushort4*)(lds + srow * PSTRIDE + col) = o;
        }
        __syncthreads();
#pragma unroll
        for (int i = 0; i < 4; ++i) {
            int cmb = wave * 4 + i;
            int kk = cmb >> 1, sub = cmb & 1;
            short8 v = *(const short8*)(lds + (sub * 16 + col16) * PSTRIDE
                                        + quad * 8 + kk * 32);
            *(short8*)(featb + (size_t)t * TILE_US + cmb * 512 + lane * 8) = v;
        }
    } else {
        // ---- WqT GEMM: 32 q-rows x 256 cols, K=256, self-converts Wk ----
        int wq = blk - nvs - ntiles;
        const float* Q; const float* Wh; int nvalid, lq0, outrow;
        if (wq < 94)       { Q = q_t; Wh = wk_t; nvalid = QT_V; lq0 = wq * 32;         outrow = lq0; }
        else if (wq < 101) { Q = q_r; Wh = wk_r; nvalid = QR_V; lq0 = (wq - 94) * 32;  outrow = QPT + lq0; }
        else               { Q = q_o; Wh = wk_o; nvalid = QO_V; lq0 = (wq - 101) * 32; outrow = QPT + QPR + lq0; }
        int row = lq0 + srow;
        bool valid = row < nvalid;
#pragma unroll
        for (int i = 0; i < 8; ++i) {
            int col = i * 32 + c8 * 4;
            float4 v;
            if (valid) v = *(const float4*)(Q + (size_t)row * D_ + col);
            else { v.x = v.y = v.z = v.w = 0.f; }
            ushort4 o;
            o.x = f2bf(v.x); o.y = f2bf(v.y); o.z = f2bf(v.z); o.w = f2bf(v.w);
            *(ushort4*)(lds + srow * PSTRIDE + col) = o;
        }
        __syncthreads();
        int c0 = wave * 64;
        f32x4 acc[2][4];
#pragma unroll
        for (int mt = 0; mt < 2; ++mt)
#pragma unroll
            for (int nt = 0; nt < 4; ++nt)
                acc[mt][nt] = f32x4{0.f, 0.f, 0.f, 0.f};
#pragma unroll
        for (int kk = 0; kk < 8; ++kk) {
            short8 a0 = *(const short8*)(lds + col16 * PSTRIDE + quad * 8 + kk * 32);
            short8 a1 = *(const short8*)(lds + (16 + col16) * PSTRIDE + quad * 8 + kk * 32);
#pragma unroll
            for (int nt = 0; nt < 4; ++nt) {
                const float* wr = Wh + (size_t)(c0 + nt * 16 + col16) * D_ + quad * 8 + kk * 32;
                float4 x = *(const float4*)(wr);
                float4 y = *(const float4*)(wr + 4);
                short8 bf;
                bf[0] = (short)f2bf(x.x); bf[1] = (short)f2bf(x.y);
                bf[2] = (short)f2bf(x.z); bf[3] = (short)f2bf(x.w);
                bf[4] = (short)f2bf(y.x); bf[5] = (short)f2bf(y.y);
                bf[6] = (short)f2bf(y.z); bf[7] = (short)f2bf(y.w);
                acc[0][nt] = __builtin_amdgcn_mfma_f32_16x16x32_bf16(a0, bf, acc[0][nt], 0, 0, 0);
                acc[1][nt] = __builtin_amdgcn_mfma_f32_16x16x32_bf16(a1, bf, acc[1][nt], 0, 0, 0);
            }
        }
#pragma unroll
        for (int mt = 0; mt < 2; ++mt)
#pragma unroll
            for (int nt = 0; nt < 4; ++nt)
#pragma unroll
                for (int r = 0; r < 4; ++r) {
                    int orow = outrow + mt * 16 + quad * 4 + r;
                    int ocol = c0 + nt * 16 + col16;
                    WqT[(size_t)orow * D_ + ocol] = f2bf(acc[mt][nt][r] * SCALE);
                }
    }
}

// ---------------- attn_main: exact R11 body (measured 69.5 us) --------------
// grid (NSPLIT, NQB, B), block 256 (4 waves x 32 q-cols)
__global__ __launch_bounds__(256, 4) void attn_main(
    const unsigned short* __restrict__ featb,
    const int* __restrict__ npts,
    const unsigned short* __restrict__ WqT,
    const float* __restrict__ vsum,
    float* __restrict__ partials, int N)
{
    __shared__ __align__(16) unsigned short lds[2][TILE_US];
    int b = blockIdx.z, qblock = blockIdx.y, chunk = blockIdx.x;
    int tid = (int)threadIdx.x;
    int wave = tid >> 6, lane = tid & 63;
    int col = lane & 15, quad = lane >> 4;

    int qp0 = qblock * 128 + wave * 32;
    int h = (qp0 < QPT) ? 0 : ((qp0 < QPT + QPR) ? 1 : 2);
    const float* vs = vsum + (size_t)h * (N + VPAD);

    int start = 0;
#pragma unroll 1
    for (int i = 0; i < b; ++i) start += npts[i];
    int end = start + npts[b];
    if (end > N) end = N;
    if (start < 0) start = 0;
    if (start > end) start = end;
    int bt0 = start >> 5, bt1 = (end + 31) >> 5;
    int ntc = (bt1 - bt0 + NSPLIT - 1) / NSPLIT;
    int ta = bt0 + chunk * ntc;
    int tb = ta + ntc; if (tb > bt1) tb = bt1;

    short8 bfrag[2][8];
#pragma unroll
    for (int qt = 0; qt < 2; ++qt) {
        const unsigned short* wr = WqT + (size_t)(qp0 + qt * 16 + col) * D_ + quad * 8;
#pragma unroll
        for (int kk = 0; kk < 8; ++kk)
            bfrag[qt][kk] = *(const short8*)(wr + kk * 32);
    }

    float den0 = 0.f, num0 = 0.f, den1 = 0.f, num1 = 0.f;
    int p = 0;
    if (ta < tb) {
        const unsigned short* g = featb + (size_t)ta * TILE_US + (wave * 4) * 512 + lane * 8;
#pragma unroll
        for (int i = 0; i < 4; ++i)
            async_cp16(g + i * 512, &lds[0][(wave * 4 + i) * 512]);
    }
#pragma unroll 1
    for (int t = ta; t < tb; ++t) {
        __syncthreads();
        if (t + 1 < tb) {
            const unsigned short* g = featb + (size_t)(t + 1) * TILE_US + (wave * 4) * 512 + lane * 8;
#pragma unroll
            for (int i = 0; i < 4; ++i)
                async_cp16(g + i * 512, &lds[p ^ 1][(wave * 4 + i) * 512]);
        }
        const unsigned short* lp = lds[p];
        f32x4 acc00 = {0.f,0.f,0.f,0.f}, acc01 = {0.f,0.f,0.f,0.f};
        f32x4 acc10 = {0.f,0.f,0.f,0.f}, acc11 = {0.f,0.f,0.f,0.f};
#pragma unroll
        for (int kk = 0; kk < 8; ++kk) {
            short8 a0 = *(const short8*)(lp + (kk * 2 + 0) * 512 + lane * 8);
            short8 a1 = *(const short8*)(lp + (kk * 2 + 1) * 512 + lane * 8);
            acc00 = __builtin_amdgcn_mfma_f32_16x16x32_bf16(a0, bfrag[0][kk], acc00, 0, 0, 0);
            acc10 = __builtin_amdgcn_mfma_f32_16x16x32_bf16(a0, bfrag[1][kk], acc10, 0, 0, 0);
            acc01 = __builtin_amdgcn_mfma_f32_16x16x32_bf16(a1, bfrag[0][kk], acc01, 0, 0, 0);
            acc11 = __builtin_amdgcn_mfma_f32_16x16x32_bf16(a1, bfrag[1][kk], acc11, 0, 0, 0);
        }
        int rb = t * 32 + quad * 4;
        f32x4 v0 = *(const f32x4*)(vs + rb);
        f32x4 v1 = *(const f32x4*)(vs + rb + 16);
        int r0 = t * 32;
        if (r0 >= start && r0 + 32 <= end) {
#pragma unroll
            for (int r = 0; r < 4; ++r) {
                float e00 = __builtin_amdgcn_exp2f(acc00[r]);
                float e01 = __builtin_amdgcn_exp2f(acc01[r]);
                float e10 = __builtin_amdgcn_exp2f(acc10[r]);
                float e11 = __builtin_amdgcn_exp2f(acc11[r]);
                den0 += e00 + e01; num0 += e00 * v0[r] + e01 * v1[r];
                den1 += e10 + e11; num1 += e10 * v0[r] + e11 * v1[r];
            }
        } else {
#pragma unroll
            for (int r = 0; r < 4; ++r) {
                int ra = rb + r, rb2 = rb + 16 + r;
                bool ma = (ra >= start) && (ra < end);
                bool mb = (rb2 >= start) && (rb2 < end);
                float e00 = ma ? __builtin_amdgcn_exp2f(acc00[r]) : 0.f;
                float e01 = mb ? __builtin_amdgcn_exp2f(acc01[r]) : 0.f;
                float e10 = ma ? __builtin_amdgcn_exp2f(acc10[r]) : 0.f;
                float e11 = mb ? __builtin_amdgcn_exp2f(acc11[r]) : 0.f;
                den0 += e00 + e01; num0 += e00 * v0[r] + e01 * v1[r];
                den1 += e10 + e11; num1 += e10 * v0[r] + e11 * v1[r];
            }
        }
        p ^= 1;
    }

    den0 += __shfl_xor(den0, 16); den0 += __shfl_xor(den0, 32);
    num0 += __shfl_xor(num0, 16); num0 += __shfl_xor(num0, 32);
    den1 += __shfl_xor(den1, 16); den1 += __shfl_xor(den1, 32);
    num1 += __shfl_xor(num1, 16); num1 += __shfl_xor(num1, 32);

    if (quad == 0) {
        size_t base = ((size_t)b * QPTOT + (qp0 + col)) * NSPLIT + chunk;
        partials[base * 2]     = den0;
        partials[base * 2 + 1] = num0;
        size_t base1 = base + (size_t)16 * NSPLIT;
        partials[base1 * 2]     = den1;
        partials[base1 * 2 + 1] = num1;
    }
}

// ---------------- combine: deterministic sum of NSPLIT (den,num) ------------
__global__ __launch_bounds__(256) void combine_k(
    const float* __restrict__ partials,
    float* __restrict__ out, int Bn)
{
    int gid = blockIdx.x * 256 + threadIdx.x;
    int total = Bn * QPTOT;
    if (gid >= total) return;
    int b = gid / QPTOT, qp = gid - b * QPTOT;
    const float* p = partials + (size_t)gid * NSPLIT * 2;
    float den = 0.f, num = 0.f;
#pragma unroll
    for (int c = 0; c < NSPLIT; ++c) { den += p[c * 2]; num += p[c * 2 + 1]; }
    float val = (den > 0.f) ? (num / den) : 0.f;
    int oidx = -1;
    if (qp < QPT) {
        if (qp < QT_V) oidx = b * QT_V + qp;
    } else if (qp < QPT + QPR) {
        int q = qp - QPT;
        if (q < QR_V) oidx = Bn * QT_V + b * QR_V + q;
    } else {
        int q = qp - QPT - QPR;
        if (q < QO_V) oidx = Bn * (QT_V + QR_V) + b;
    }
    if (oidx >= 0) out[oidx] = val;
}

extern "C" void kernel_launch(void* const* d_in, const int* in_sizes, int n_in,
                              void* d_out, int out_size, void* d_ws, size_t ws_size,
                              hipStream_t stream)
{
    const float* feat = (const float*)d_in[0];
    const int* npts   = (const int*)d_in[1];
    const float* q_t  = (const float*)d_in[2];
    const float* wk_t = (const float*)d_in[3];
    const float* wv_t = (const float*)d_in[4];
    const float* q_r  = (const float*)d_in[5];
    const float* wk_r = (const float*)d_in[6];
    const float* wv_r = (const float*)d_in[7];
    const float* q_o  = (const float*)d_in[8];
    const float* wk_o = (const float*)d_in[9];
    const float* wv_o = (const float*)d_in[10];

    int N  = in_sizes[0] / D_;
    int Bn = in_sizes[1];
    int ntiles = (N + 31) / 32;
    int nvs = (N + 127) / 128;

    char* ws = (char*)d_ws;
    size_t off = 0;
    unsigned short* WqT = (unsigned short*)(ws + off);
    off += (size_t)QPTOT * D_ * sizeof(unsigned short);
    off = (off + 255) & ~(size_t)255;
    unsigned short* featb = (unsigned short*)(ws + off);
    off += (size_t)ntiles * TILE_US * sizeof(unsigned short);
    off = (off + 255) & ~(size_t)255;
    float* vsum = (float*)(ws + off);
    off += (size_t)3 * (N + VPAD) * sizeof(float);
    off = (off + 255) & ~(size_t)255;
    float* partials = (float*)(ws + off);
    off += (size_t)Bn * QPTOT * NSPLIT * 2 * sizeof(float);
    (void)ws_size;

    prep<<<nvs + ntiles + WQ_TILES, 256, 0, stream>>>(
        feat, q_t, q_r, q_o, wk_t, wk_r, wk_o, wv_t, wv_r, wv_o,
        featb, vsum, WqT, N, ntiles, nvs);

    dim3 grid(NSPLIT, NQB, Bn);
    attn_main<<<grid, 256, 0, stream>>>(featb, npts, WqT, vsum, partials, N);

    int total = Bn * QPTOT;
    combine_k<<<(total + 255) / 256, 256, 0, stream>>>(partials, (float*)d_out, Bn);
}

// Round 15
// 179.417 us; speedup vs baseline: 1.1040x; 1.1040x over previous
//
#include <hip/hip_runtime.h>

typedef __attribute__((ext_vector_type(8))) short short8;
typedef __attribute__((ext_vector_type(4))) float f32x4;
typedef unsigned int u32;

#define D_ 256
#define QT_V 3000
#define QR_V 216
#define QO_V 1
#define QPT 3008          // padded head-t rows (94 tiles)
#define QPR 224           // padded head-r rows (7 tiles)
#define QPO 96            // padded head-o rows (3 tiles)
#define QPTOT 3328        // 26 * 128
#define NQB 26            // attn qblocks of 128 cols
#define WQ_TILES 104
#define NSPLIT 8          /* measured best: 8 > {5,16} */
#define VPAD 32
#define SCALE 0.09016844005556021f   /* log2(e)/16 */
#define TILE_US 8192      /* ushorts per 32x256 bf16 frag-linear tile */
#define PSTRIDE 264       /* padded LDS row stride in ushorts */

__device__ __forceinline__ unsigned short f2bf(float f) {
    union { float f; unsigned int i; } u; u.f = f;
    unsigned int i = u.i + 0x7fffu + ((u.i >> 16) & 1u);
    return (unsigned short)(i >> 16);
}

__device__ __forceinline__ void async_cp16(const unsigned short* g, unsigned short* l) {
    __builtin_amdgcn_global_load_lds((const __attribute__((address_space(1))) u32*)g,
                                     (__attribute__((address_space(3))) u32*)l, 16, 0, 0);
}

// ---------------- prep_w: wvsum (3 blocks) + vsum pad zero (1 block) --------
__global__ __launch_bounds__(256) void prep_w(
    const float* __restrict__ wv_t, const float* __restrict__ wv_r,
    const float* __restrict__ wv_o,
    float* __restrict__ wvsum, float* __restrict__ vsum, int N)
{
    int blk = blockIdx.x, tid = (int)threadIdx.x;
    int wave = tid >> 6, lane = tid & 63;
    if (blk < 3) {
        const float* Wv = (blk == 0) ? wv_t : ((blk == 1) ? wv_r : wv_o);
        for (int f0 = wave * 4; f0 < 256; f0 += 16) {
            int f = f0 + (lane >> 4);
            const float* base = Wv + (size_t)f * D_;
            float s = 0.f;
#pragma unroll
            for (int p = 0; p < 4; ++p) {
                float4 x = *(const float4*)(base + p * 64 + (lane & 15) * 4);
                s += x.x + x.y + x.z + x.w;
            }
            s += __shfl_xor(s, 1); s += __shfl_xor(s, 2);
            s += __shfl_xor(s, 4); s += __shfl_xor(s, 8);
            if ((lane & 15) == 0) wvsum[blk * 256 + f] = s;
        }
    } else {
        if (tid < 3 * VPAD) {
            int hh = tid / VPAD, i = tid % VPAD;
            vsum[(size_t)hh * (N + VPAD) + N + i] = 0.f;
        }
    }
}

// ------- prep_mid: [0,ntiles) feat->featb + inline f32 vsum; then WqT GEMM --
__global__ __launch_bounds__(256) void prep_mid(
    const float* __restrict__ feat,
    const float* __restrict__ wvsum,
    const float* __restrict__ q_t, const float* __restrict__ q_r,
    const float* __restrict__ q_o,
    const float* __restrict__ wk_t, const float* __restrict__ wk_r,
    const float* __restrict__ wk_o,
    unsigned short* __restrict__ featb,
    float* __restrict__ vsum,
    unsigned short* __restrict__ WqT,
    int N, int ntiles)
{
    __shared__ __align__(16) unsigned short lds[32 * PSTRIDE];
    int blk = blockIdx.x, tid = (int)threadIdx.x;
    int srow = tid >> 3, c8 = tid & 7;
    int wave = tid >> 6, lane = tid & 63;
    int col16 = lane & 15, quad = lane >> 4;

    if (blk < ntiles) {
        int t = blk;
        int row = t * 32 + srow;
        bool valid = row < N;
        float p0 = 0.f, p1 = 0.f, p2 = 0.f;
#pragma unroll
        for (int i = 0; i < 8; ++i) {
            int col = i * 32 + c8 * 4;
            float4 v;
            if (valid) v = *(const float4*)(feat + (size_t)row * D_ + col);
            else { v.x = v.y = v.z = v.w = 0.f; }
            ushort4 o;
            o.x = f2bf(v.x); o.y = f2bf(v.y); o.z = f2bf(v.z); o.w = f2bf(v.w);
            *(ushort4*)(lds + srow * PSTRIDE + col) = o;
            float4 w0 = *(const float4*)(wvsum + col);
            float4 w1 = *(const float4*)(wvsum + 256 + col);
            float4 w2 = *(const float4*)(wvsum + 512 + col);
            p0 += v.x * w0.x + v.y * w0.y + v.z * w0.z + v.w * w0.w;
            p1 += v.x * w1.x + v.y * w1.y + v.z * w1.z + v.w * w1.w;
            p2 += v.x * w2.x + v.y * w2.y + v.z * w2.z + v.w * w2.w;
        }
        p0 += __shfl_xor(p0, 1); p0 += __shfl_xor(p0, 2); p0 += __shfl_xor(p0, 4);
        p1 += __shfl_xor(p1, 1); p1 += __shfl_xor(p1, 2); p1 += __shfl_xor(p1, 4);
        p2 += __shfl_xor(p2, 1); p2 += __shfl_xor(p2, 2); p2 += __shfl_xor(p2, 4);
        if (c8 == 0 && valid) {
            vsum[0 * (size_t)(N + VPAD) + row] = p0;
            vsum[1 * (size_t)(N + VPAD) + row] = p1;
            vsum[2 * (size_t)(N + VPAD) + row] = p2;
        }
        __syncthreads();
#pragma unroll
        for (int i = 0; i < 4; ++i) {
            int cmb = wave * 4 + i;
            int kk = cmb >> 1, sub = cmb & 1;
            short8 v = *(const short8*)(lds + (sub * 16 + col16) * PSTRIDE
                                        + quad * 8 + kk * 32);
            *(short8*)(featb + (size_t)t * TILE_US + cmb * 512 + lane * 8) = v;
        }
    } else {
        int wq = blk - ntiles;
        const float* Q; const float* Wh; int nvalid, lq0, outrow;
        if (wq < 94)       { Q = q_t; Wh = wk_t; nvalid = QT_V; lq0 = wq * 32;         outrow = lq0; }
        else if (wq < 101) { Q = q_r; Wh = wk_r; nvalid = QR_V; lq0 = (wq - 94) * 32;  outrow = QPT + lq0; }
        else               { Q = q_o; Wh = wk_o; nvalid = QO_V; lq0 = (wq - 101) * 32; outrow = QPT + QPR + lq0; }
        int row = lq0 + srow;
        bool valid = row < nvalid;
#pragma unroll
        for (int i = 0; i < 8; ++i) {
            int col = i * 32 + c8 * 4;
            float4 v;
            if (valid) v = *(const float4*)(Q + (size_t)row * D_ + col);
            else { v.x = v.y = v.z = v.w = 0.f; }
            ushort4 o;
            o.x = f2bf(v.x); o.y = f2bf(v.y); o.z = f2bf(v.z); o.w = f2bf(v.w);
            *(ushort4*)(lds + srow * PSTRIDE + col) = o;
        }
        __syncthreads();
        int c0 = wave * 64;
        f32x4 acc[2][4];
#pragma unroll
        for (int mt = 0; mt < 2; ++mt)
#pragma unroll
            for (int nt = 0; nt < 4; ++nt)
                acc[mt][nt] = f32x4{0.f, 0.f, 0.f, 0.f};
#pragma unroll
        for (int kk = 0; kk < 8; ++kk) {
            short8 a0 = *(const short8*)(lds + col16 * PSTRIDE + quad * 8 + kk * 32);
            short8 a1 = *(const short8*)(lds + (16 + col16) * PSTRIDE + quad * 8 + kk * 32);
#pragma unroll
            for (int nt = 0; nt < 4; ++nt) {
                const float* wr = Wh + (size_t)(c0 + nt * 16 + col16) * D_ + quad * 8 + kk * 32;
                float4 x = *(const float4*)(wr);
                float4 y = *(const float4*)(wr + 4);
                short8 bf;
                bf[0] = (short)f2bf(x.x); bf[1] = (short)f2bf(x.y);
                bf[2] = (short)f2bf(x.z); bf[3] = (short)f2bf(x.w);
                bf[4] = (short)f2bf(y.x); bf[5] = (short)f2bf(y.y);
                bf[6] = (short)f2bf(y.z); bf[7] = (short)f2bf(y.w);
                acc[0][nt] = __builtin_amdgcn_mfma_f32_16x16x32_bf16(a0, bf, acc[0][nt], 0, 0, 0);
                acc[1][nt] = __builtin_amdgcn_mfma_f32_16x16x32_bf16(a1, bf, acc[1][nt], 0, 0, 0);
            }
        }
#pragma unroll
        for (int mt = 0; mt < 2; ++mt)
#pragma unroll
            for (int nt = 0; nt < 4; ++nt)
#pragma unroll
                for (int r = 0; r < 4; ++r) {
                    int orow = outrow + mt * 16 + quad * 4 + r;
                    int ocol = c0 + nt * 16 + col16;
                    WqT[(size_t)orow * D_ + ocol] = f2bf(acc[mt][nt][r] * SCALE);
                }
    }
}

// ---------------- attn_main: exact R4/R11 body (measured 67.7-69.5 us) ------
// grid (NSPLIT, NQB, B), block 256 (4 waves x 32 q-cols)
__global__ __launch_bounds__(256, 4) void attn_main(
    const unsigned short* __restrict__ featb,
    const int* __restrict__ npts,
    const unsigned short* __restrict__ WqT,
    const float* __restrict__ vsum,
    float* __restrict__ partials, int N)
{
    __shared__ __align__(16) unsigned short lds[2][TILE_US];
    int b = blockIdx.z, qblock = blockIdx.y, chunk = blockIdx.x;
    int tid = (int)threadIdx.x;
    int wave = tid >> 6, lane = tid & 63;
    int col = lane & 15, quad = lane >> 4;

    int qp0 = qblock * 128 + wave * 32;
    int h = (qp0 < QPT) ? 0 : ((qp0 < QPT + QPR) ? 1 : 2);
    const float* vs = vsum + (size_t)h * (N + VPAD);

    int start = 0;
#pragma unroll 1
    for (int i = 0; i < b; ++i) start += npts[i];
    int end = start + npts[b];
    if (end > N) end = N;
    if (start < 0) start = 0;
    if (start > end) start = end;
    int bt0 = start >> 5, bt1 = (end + 31) >> 5;
    int ntc = (bt1 - bt0 + NSPLIT - 1) / NSPLIT;
    int ta = bt0 + chunk * ntc;
    int tb = ta + ntc; if (tb > bt1) tb = bt1;

    short8 bfrag[2][8];
#pragma unroll
    for (int qt = 0; qt < 2; ++qt) {
        const unsigned short* wr = WqT + (size_t)(qp0 + qt * 16 + col) * D_ + quad * 8;
#pragma unroll
        for (int kk = 0; kk < 8; ++kk)
            bfrag[qt][kk] = *(const short8*)(wr + kk * 32);
    }

    float den0 = 0.f, num0 = 0.f, den1 = 0.f, num1 = 0.f;
    int p = 0;
    if (ta < tb) {
        const unsigned short* g = featb + (size_t)ta * TILE_US + (wave * 4) * 512 + lane * 8;
#pragma unroll
        for (int i = 0; i < 4; ++i)
            async_cp16(g + i * 512, &lds[0][(wave * 4 + i) * 512]);
    }
#pragma unroll 1
    for (int t = ta; t < tb; ++t) {
        __syncthreads();
        if (t + 1 < tb) {
            const unsigned short* g = featb + (size_t)(t + 1) * TILE_US + (wave * 4) * 512 + lane * 8;
#pragma unroll
            for (int i = 0; i < 4; ++i)
                async_cp16(g + i * 512, &lds[p ^ 1][(wave * 4 + i) * 512]);
        }
        const unsigned short* lp = lds[p];
        f32x4 acc00 = {0.f,0.f,0.f,0.f}, acc01 = {0.f,0.f,0.f,0.f};
        f32x4 acc10 = {0.f,0.f,0.f,0.f}, acc11 = {0.f,0.f,0.f,0.f};
#pragma unroll
        for (int kk = 0; kk < 8; ++kk) {
            short8 a0 = *(const short8*)(lp + (kk * 2 + 0) * 512 + lane * 8);
            short8 a1 = *(const short8*)(lp + (kk * 2 + 1) * 512 + lane * 8);
            acc00 = __builtin_amdgcn_mfma_f32_16x16x32_bf16(a0, bfrag[0][kk], acc00, 0, 0, 0);
            acc10 = __builtin_amdgcn_mfma_f32_16x16x32_bf16(a0, bfrag[1][kk], acc10, 0, 0, 0);
            acc01 = __builtin_amdgcn_mfma_f32_16x16x32_bf16(a1, bfrag[0][kk], acc01, 0, 0, 0);
            acc11 = __builtin_amdgcn_mfma_f32_16x16x32_bf16(a1, bfrag[1][kk], acc11, 0, 0, 0);
        }
        int rb = t * 32 + quad * 4;
        f32x4 v0 = *(const f32x4*)(vs + rb);
        f32x4 v1 = *(const f32x4*)(vs + rb + 16);
        int r0 = t * 32;
        if (r0 >= start && r0 + 32 <= end) {
#pragma unroll
            for (int r = 0; r < 4; ++r) {
                float e00 = __builtin_amdgcn_exp2f(acc00[r]);
                float e01 = __builtin_amdgcn_exp2f(acc01[r]);
                float e10 = __builtin_amdgcn_exp2f(acc10[r]);
                float e11 = __builtin_amdgcn_exp2f(acc11[r]);
                den0 += e00 + e01; num0 += e00 * v0[r] + e01 * v1[r];
                den1 += e10 + e11; num1 += e10 * v0[r] + e11 * v1[r];
            }
        } else {
#pragma unroll
            for (int r = 0; r < 4; ++r) {
                int ra = rb + r, rb2 = rb + 16 + r;
                bool ma = (ra >= start) && (ra < end);
                bool mb = (rb2 >= start) && (rb2 < end);
                float e00 = ma ? __builtin_amdgcn_exp2f(acc00[r]) : 0.f;
                float e01 = mb ? __builtin_amdgcn_exp2f(acc01[r]) : 0.f;
                float e10 = ma ? __builtin_amdgcn_exp2f(acc10[r]) : 0.f;
                float e11 = mb ? __builtin_amdgcn_exp2f(acc11[r]) : 0.f;
                den0 += e00 + e01; num0 += e00 * v0[r] + e01 * v1[r];
                den1 += e10 + e11; num1 += e10 * v0[r] + e11 * v1[r];
            }
        }
        p ^= 1;
    }

    den0 += __shfl_xor(den0, 16); den0 += __shfl_xor(den0, 32);
    num0 += __shfl_xor(num0, 16); num0 += __shfl_xor(num0, 32);
    den1 += __shfl_xor(den1, 16); den1 += __shfl_xor(den1, 32);
    num1 += __shfl_xor(num1, 16); num1 += __shfl_xor(num1, 32);

    if (quad == 0) {
        size_t base = ((size_t)b * QPTOT + (qp0 + col)) * NSPLIT + chunk;
        partials[base * 2]     = den0;
        partials[base * 2 + 1] = num0;
        size_t base1 = base + (size_t)16 * NSPLIT;
        partials[base1 * 2]     = den1;
        partials[base1 * 2 + 1] = num1;
    }
}

// ---------------- combine: deterministic sum of NSPLIT (den,num) ------------
__global__ __launch_bounds__(256) void combine_k(
    const float* __restrict__ partials,
    float* __restrict__ out, int Bn)
{
    int gid = blockIdx.x * 256 + threadIdx.x;
    int total = Bn * QPTOT;
    if (gid >= total) return;
    int b = gid / QPTOT, qp = gid - b * QPTOT;
    const float* p = partials + (size_t)gid * NSPLIT * 2;
    float den = 0.f, num = 0.f;
#pragma unroll
    for (int c = 0; c < NSPLIT; ++c) { den += p[c * 2]; num += p[c * 2 + 1]; }
    float val = (den > 0.f) ? (num / den) : 0.f;
    int oidx = -1;
    if (qp < QPT) {
        if (qp < QT_V) oidx = b * QT_V + qp;
    } else if (qp < QPT + QPR) {
        int q = qp - QPT;
        if (q < QR_V) oidx = Bn * QT_V + b * QR_V + q;
    } else {
        int q = qp - QPT - QPR;
        if (q < QO_V) oidx = Bn * (QT_V + QR_V) + b;
    }
    if (oidx >= 0) out[oidx] = val;
}

extern "C" void kernel_launch(void* const* d_in, const int* in_sizes, int n_in,
                              void* d_out, int out_size, void* d_ws, size_t ws_size,
                              hipStream_t stream)
{
    const float* feat = (const float*)d_in[0];
    const int* npts   = (const int*)d_in[1];
    const float* q_t  = (const float*)d_in[2];
    const float* wk_t = (const float*)d_in[3];
    const float* wv_t = (const float*)d_in[4];
    const float* q_r  = (const float*)d_in[5];
    const float* wk_r = (const float*)d_in[6];
    const float* wv_r = (const float*)d_in[7];
    const float* q_o  = (const float*)d_in[8];
    const float* wk_o = (const float*)d_in[9];
    const float* wv_o = (const float*)d_in[10];

    int N  = in_sizes[0] / D_;
    int Bn = in_sizes[1];
    int ntiles = (N + 31) / 32;

    char* ws = (char*)d_ws;
    size_t off = 0;
    unsigned short* WqT = (unsigned short*)(ws + off);
    off += (size_t)QPTOT * D_ * sizeof(unsigned short);
    off = (off + 255) & ~(size_t)255;
    unsigned short* featb = (unsigned short*)(ws + off);
    off += (size_t)ntiles * TILE_US * sizeof(unsigned short);
    off = (off + 255) & ~(size_t)255;
    float* wvsum = (float*)(ws + off);
    off += 3 * D_ * sizeof(float);
    off = (off + 255) & ~(size_t)255;
    float* vsum = (float*)(ws + off);
    off += (size_t)3 * (N + VPAD) * sizeof(float);
    off = (off + 255) & ~(size_t)255;
    float* partials = (float*)(ws + off);
    off += (size_t)Bn * QPTOT * NSPLIT * 2 * sizeof(float);
    (void)ws_size;

    prep_w<<<4, 256, 0, stream>>>(wv_t, wv_r, wv_o, wvsum, vsum, N);
    prep_mid<<<ntiles + WQ_TILES, 256, 0, stream>>>(
        feat, wvsum, q_t, q_r, q_o, wk_t, wk_r, wk_o,
        featb, vsum, WqT, N, ntiles);

    dim3 grid(NSPLIT, NQB, Bn);
    attn_main<<<grid, 256, 0, stream>>>(featb, npts, WqT, vsum, partials, N);

    int total = Bn * QPTOT;
    combine_k<<<(total + 255) / 256, 256, 0, stream>>>(partials, (float*)d_out, Bn);
}